// Round 9
// baseline (1893.632 us; speedup 1.0000x reference)
//
#include <hip/hip_runtime.h>
#include <hip/hip_bf16.h>

// Problem constants (from reference)
#define N_NODES 50000
#define N_EDGES 150000
#define NODE_IN 64
#define EDGE_IN 16
#define DD 32          // node feature dim
#define EHID 128       // edge-network hidden
#define STEPS 3
#define EPB 64         // edges per fused_msg block
#define NSCAN 196      // ceil(N_NODES/256) scan blocks

// Device-verified harness dtypes: float inputs fp32, edge_index int32, output fp32.
__device__ __forceinline__ ushort f2b(float f) {
    __hip_bfloat16 b = __float2bfloat16(f);   // RNE
    return *reinterpret_cast<ushort*>(&b);
}
__device__ __forceinline__ float b2f(ushort u) {
    unsigned int x = ((unsigned int)u) << 16;
    return __uint_as_float(x);
}

typedef __bf16 bf16x8 __attribute__((ext_vector_type(8)));
typedef float  f32x4  __attribute__((ext_vector_type(4)));
typedef float  f32x16 __attribute__((ext_vector_type(16)));

#define LDA  136   // As leading dim (ushorts); 272B rows: 16B-aligned, bank-even
#define HPAD 36    // Hs leading dim (floats)
#define PLD  33    // P leading dim (floats) — odd stride breaks bank aliasing

// ---------------------------------------------------------------------------
// setup: merged prep + node_init + hist.
// R9 prep: we2B repacked for 32x32x16 fragments:
//   frag f = bn*16 + nt32*8 + ks; lane l -> B[n=bn*64+nt32*32+(l&31)][k=ks*16+(l>>5)*8+j]
__global__ __launch_bounds__(256) void setup(const float* __restrict__ we2,
                                             const float* __restrict__ we1,
                                             const float* __restrict__ wroot,
                                             const float* __restrict__ wih,
                                             const float* __restrict__ whh,
                                             ushort* __restrict__ we2B,
                                             ushort* __restrict__ we1B,
                                             ushort* __restrict__ wgB,
                                             const float* __restrict__ x,
                                             const float* __restrict__ Wn,
                                             const float* __restrict__ bn,
                                             float* __restrict__ h,
                                             const int* __restrict__ ei,
                                             int* __restrict__ cnt) {
    __shared__ float Wns[NODE_IN * DD];   // node_init blocks only
    __shared__ float bns[DD];
    int b = blockIdx.x, t = threadIdx.x;

    if (b < 70) {   // ---- prep ----
        int i = b * 256 + t;
        if (i < 16384) {
            int l = i & 63, f = i >> 6;           // f = bn*16 + nt32*8 + ks
            int ks = f & 7, nt = (f >> 3) & 1, bq = f >> 4;
            int n = bq * 64 + nt * 32 + (l & 31);
            int k0 = ks * 16 + (l >> 5) * 8;
            ushort tmp[8];
#pragma unroll
            for (int j = 0; j < 8; ++j) tmp[j] = f2b(we2[(size_t)(k0 + j) * 1024 + n]);
            *(uint4*)(we2B + (size_t)i * 8) = *(uint4*)tmp;
        } else if (i < 16896) {
            int u = i - 16384;
            int l = u & 63, nt = u >> 6;
            int lr = l & 15, lg = l >> 4;
            int n = nt * 16 + lr;
            ushort tmp[8];
#pragma unroll
            for (int j = 0; j < 8; ++j) {
                int k = lg * 8 + j;
                tmp[j] = (k < EDGE_IN) ? f2b(we1[(size_t)k * EHID + n]) : (ushort)0;
            }
            *(uint4*)(we1B + (size_t)u * 8) = *(uint4*)tmp;
        } else if (i < 17792) {
            int u = i - 16896;
            int l = u & 63;
            int lr = l & 15, lg = l >> 4;
            ushort tmp[8];
            if (u < 128) {            // Wroot [i][o] row-major
                int nt = u >> 6;
#pragma unroll
                for (int j = 0; j < 8; ++j)
                    tmp[j] = f2b(wroot[(size_t)(lg * 8 + j) * DD + nt * 16 + lr]);
            } else if (u < 512) {     // Wih
                int nt = (u - 128) >> 6;
#pragma unroll
                for (int j = 0; j < 8; ++j)
                    tmp[j] = f2b(wih[(size_t)(nt * 16 + lr) * DD + lg * 8 + j]);
            } else {                  // Whh
                int nt = (u - 512) >> 6;
#pragma unroll
                for (int j = 0; j < 8; ++j)
                    tmp[j] = f2b(whh[(size_t)(nt * 16 + lr) * DD + lg * 8 + j]);
            }
            *(uint4*)(wgB + (size_t)u * 8) = *(uint4*)tmp;
        }
    } else if (b < 266) {   // ---- node_init ----
        for (int i = t; i < NODE_IN * DD; i += 256) Wns[i] = Wn[i];
        if (t < DD) bns[t] = bn[t];
        __syncthreads();
        int n = (b - 70) * 256 + t;
        if (n >= N_NODES) return;
        float xr[NODE_IN];
        const float4* xp = (const float4*)(x + (size_t)n * NODE_IN);
#pragma unroll
        for (int q = 0; q < NODE_IN / 4; ++q) *(float4*)&xr[q * 4] = xp[q];
        float out[DD];
#pragma unroll
        for (int o = 0; o < DD; ++o) {
            float s = bns[o];
#pragma unroll
            for (int i = 0; i < NODE_IN; ++i) s += xr[i] * Wns[i * DD + o];
            out[o] = fmaxf(s, 0.f);
        }
        float4* hp = (float4*)(h + (size_t)n * DD);
#pragma unroll
        for (int q = 0; q < DD / 4; ++q) hp[q] = *(float4*)&out[q * 4];
    } else {   // ---- hist ----
        int e = (b - 266) * 256 + t;
        if (e < N_EDGES) atomicAdd(&cnt[ei[N_EDGES + e]], 1);
    }
}

// ---------------------------------------------------------------------------
// Multi-block exclusive scan + fill (proven R7/R8 form).
__global__ __launch_bounds__(256) void scan1(int* __restrict__ cnt,
                                             int* __restrict__ bsum) {
    __shared__ int wsum[4];
    int b = blockIdx.x, t = threadIdx.x;
    int lane = t & 63, wid = t >> 6;
    int i = b * 256 + t;
    int v = (i < N_NODES) ? cnt[i] : 0;
    int s = v;
#pragma unroll
    for (int off = 1; off < 64; off <<= 1) {
        int u = __shfl_up(s, off);
        if (lane >= off) s += u;
    }
    if (lane == 63) wsum[wid] = s;
    __syncthreads();
    if (t == 0) {
        int a = 0;
#pragma unroll
        for (int k = 0; k < 4; ++k) { int tmp = wsum[k]; wsum[k] = a; a += tmp; }
    }
    __syncthreads();
    int excl = s - v + wsum[wid];
    if (i < N_NODES) cnt[i] = excl;
    if (t == 255) bsum[b] = excl + v;
}

__global__ __launch_bounds__(256) void scan2(int* __restrict__ bsum) {
    __shared__ int wsum[4];
    int t = threadIdx.x;
    int lane = t & 63, wid = t >> 6;
    int v = (t < NSCAN) ? bsum[t] : 0;
    int s = v;
#pragma unroll
    for (int off = 1; off < 64; off <<= 1) {
        int u = __shfl_up(s, off);
        if (lane >= off) s += u;
    }
    if (lane == 63) wsum[wid] = s;
    __syncthreads();
    if (t == 0) {
        int a = 0;
#pragma unroll
        for (int k = 0; k < 4; ++k) { int tmp = wsum[k]; wsum[k] = a; a += tmp; }
    }
    __syncthreads();
    if (t < NSCAN) bsum[t] = s - v + wsum[wid];
}

__global__ __launch_bounds__(256) void scan3(const int* __restrict__ cnt,
                                             const int* __restrict__ bsum,
                                             int* __restrict__ off,
                                             int* __restrict__ cur) {
    int i = blockIdx.x * 256 + threadIdx.x;
    if (i < N_NODES) {
        int o = cnt[i] + bsum[blockIdx.x];
        off[i] = o;
        cur[i] = o;
    }
}

__global__ __launch_bounds__(256) void scatter_fill(const int* __restrict__ ei,
                                                    int* __restrict__ cur,
                                                    int* __restrict__ perm,
                                                    int* __restrict__ srcs,
                                                    int* __restrict__ dsts) {
    int e = blockIdx.x * 256 + threadIdx.x;
    if (e >= N_EDGES) return;
    int d = ei[N_EDGES + e];
    int pos = atomicAdd(&cur[d], 1);
    perm[pos] = e;
    srcs[pos] = ei[e];
    dsts[pos] = d;
}

// ---------------------------------------------------------------------------
// fused_msg R9: 32x32x16 MFMA phase B, bn-split across waves, barrier-free
// main loop (B streamed from L2 in regs — no staging, no per-bn drains).
// fp32 partials P[4][64][33] reduced cross-wave, then SEGMENTED scatter:
// dst-sorted edges => block owns contiguous node range; interior nodes get
// plain stores, boundary nodes atomicAdd (~2/block vs 4.8M/dispatch before).
// 32x32x16 layouts: A[m=l&31][k=(l>>5)*8+j], B[n=l&31][k=(l>>5)*8+j],
// D[col=l&31][row=(r&3)+8*(r>>2)+4*(l>>5)]  (guide §3, m74/m101).
__global__ __launch_bounds__(256, 4) void fused_msg(const float* __restrict__ ea,
                                                    const ushort* __restrict__ we1B,
                                                    const float* __restrict__ be1,
                                                    const ushort* __restrict__ we2B,
                                                    const float* __restrict__ be2,
                                                    const int* __restrict__ perm,
                                                    const int* __restrict__ srcs,
                                                    const int* __restrict__ dsts,
                                                    const int* __restrict__ off,
                                                    const float* __restrict__ h,
                                                    float* __restrict__ agg) {
    __shared__ __attribute__((aligned(16))) char UM[33792];
    ushort* As = (ushort*)UM;                 // [64][136] bf16, 17408 B (phase A->B)
    float*  Hs = (float*)(UM + 17408);        // [64][36] fp32, 9216 B   (phase B)
    float*  P  = (float*)UM;                  // [4][64][33] fp32, 33792 B (tail)
    __shared__ float b1s[EHID];
    __shared__ float be2s[DD * DD];

    int t = threadIdx.x;
    int w = t >> 6, l = t & 63;
    int lr = l & 15, lg = l >> 4;
    int l31 = l & 31, hi5 = l >> 5;
    int e0 = blockIdx.x * EPB;

    if (t < EHID) b1s[t] = be1[t];
    for (int i = t; i < DD * DD; i += 256) be2s[i] = be2[i];

    // Gather h[srcs[e]] into Hs (4 threads per edge row) — region disjoint from As
    {
        int row = t >> 2, qtr = t & 3;
        int e = e0 + row;
        float4* hd = (float4*)(Hs + row * HPAD) + qtr * 2;
        if (e < N_EDGES) {
            const float4* hr = (const float4*)(h + (size_t)srcs[e] * DD) + qtr * 2;
            hd[0] = hr[0];
            hd[1] = hr[1];
        } else {
            float4 z = make_float4(0.f, 0.f, 0.f, 0.f);
            hd[0] = z; hd[1] = z;
        }
    }

    // Phase A input fragment via perm (16x16x32 layout: lane&15 rows, lg k-groups)
    bf16x8 afe;
    {
        int e = e0 + w * 16 + lr;
        ushort tmp[8] = {0, 0, 0, 0, 0, 0, 0, 0};
        if (lg < 2 && e < N_EDGES) {
            int pe = perm[e];
            const float4* p = (const float4*)(ea + (size_t)pe * EDGE_IN + lg * 8);
            float4 a = p[0], b = p[1];
            tmp[0] = f2b(a.x); tmp[1] = f2b(a.y); tmp[2] = f2b(a.z); tmp[3] = f2b(a.w);
            tmp[4] = f2b(b.x); tmp[5] = f2b(b.y); tmp[6] = f2b(b.z); tmp[7] = f2b(b.w);
        }
        afe = *(bf16x8*)tmp;
    }
    __syncthreads();   // (1) b1s/be2s ready

    // Phase A: g = relu(ea@We1+be1) -> bf16 As[64][128] (wave w owns rows w*16..+16)
#pragma unroll
    for (int nt = 0; nt < 8; ++nt) {
        bf16x8 bfe = *(const bf16x8*)(we1B + (size_t)((nt << 6) + l) * 8);
        int kh = nt * 16 + lr;
        float bb = b1s[kh];
        f32x4 acc = (f32x4){0.f, 0.f, 0.f, 0.f};
        acc = __builtin_amdgcn_mfma_f32_16x16x32_bf16(afe, bfe, acc, 0, 0, 0);
#pragma unroll
        for (int r = 0; r < 4; ++r)
            As[(size_t)(w * 16 + lg * 4 + r) * LDA + kh] = f2b(fmaxf(acc[r] + bb, 0.f));
    }
    __syncthreads();   // (2) As + Hs complete — LAST barrier before phase B

    // Phase B: barrier-free. Wave w owns bn = w*4..w*4+3 for ALL 64 edges.
    float m0[16], m1[16];   // fp32 partial m for edge rows (l-dependent), col l31
#pragma unroll
    for (int r = 0; r < 16; ++r) { m0[r] = 0.f; m1[r] = 0.f; }

#pragma unroll
    for (int q = 0; q < 4; ++q) {
        int bn = w * 4 + q;
        float bv0 = be2s[bn * 64 + l31];
        float bv1 = be2s[bn * 64 + 32 + l31];

        // nt32 = 0 (i = 2bn)
        {
            f32x16 a0 = {0.f}, a1 = {0.f};
#pragma unroll
            for (int ks = 0; ks < 8; ++ks) {
                bf16x8 bf = *(const bf16x8*)(we2B + ((size_t)(bn * 16 + ks) * 64 + l) * 8);
                bf16x8 x0 = *(const bf16x8*)(As + (size_t)l31 * LDA + ks * 16 + hi5 * 8);
                bf16x8 x1 = *(const bf16x8*)(As + (size_t)(32 + l31) * LDA + ks * 16 + hi5 * 8);
                a0 = __builtin_amdgcn_mfma_f32_32x32x16_bf16(x0, bf, a0, 0, 0, 0);
                a1 = __builtin_amdgcn_mfma_f32_32x32x16_bf16(x1, bf, a1, 0, 0, 0);
            }
#pragma unroll
            for (int r = 0; r < 16; ++r) {
                int rr = (r & 3) + 8 * (r >> 2) + 4 * hi5;
                m0[r] += Hs[(size_t)rr * HPAD + 2 * bn]        * (a0[r] + bv0);
                m1[r] += Hs[(size_t)(32 + rr) * HPAD + 2 * bn] * (a1[r] + bv0);
            }
        }
        // nt32 = 1 (i = 2bn+1)
        {
            f32x16 a0 = {0.f}, a1 = {0.f};
#pragma unroll
            for (int ks = 0; ks < 8; ++ks) {
                bf16x8 bf = *(const bf16x8*)(we2B + ((size_t)(bn * 16 + 8 + ks) * 64 + l) * 8);
                bf16x8 x0 = *(const bf16x8*)(As + (size_t)l31 * LDA + ks * 16 + hi5 * 8);
                bf16x8 x1 = *(const bf16x8*)(As + (size_t)(32 + l31) * LDA + ks * 16 + hi5 * 8);
                a0 = __builtin_amdgcn_mfma_f32_32x32x16_bf16(x0, bf, a0, 0, 0, 0);
                a1 = __builtin_amdgcn_mfma_f32_32x32x16_bf16(x1, bf, a1, 0, 0, 0);
            }
#pragma unroll
            for (int r = 0; r < 16; ++r) {
                int rr = (r & 3) + 8 * (r >> 2) + 4 * hi5;
                m0[r] += Hs[(size_t)rr * HPAD + 2 * bn + 1]        * (a0[r] + bv1);
                m1[r] += Hs[(size_t)(32 + rr) * HPAD + 2 * bn + 1] * (a1[r] + bv1);
            }
        }
    }

    __syncthreads();   // (3) all folds done reading As/Hs -> region becomes P
#pragma unroll
    for (int r = 0; r < 16; ++r) {
        int rr = (r & 3) + 8 * (r >> 2) + 4 * hi5;
        P[((size_t)w * 64 + rr) * PLD + l31]      = m0[r];
        P[((size_t)w * 64 + 32 + rr) * PLD + l31] = m1[r];
    }
    __syncthreads();   // (4) P complete

    // Segmented reduce + scatter: thread (slot s = t>>5, col c = t&31).
    {
        int c = t & 31;
        int nlo = dsts[e0];
        int elast = e0 + EPB - 1;
        if (elast >= N_EDGES) elast = N_EDGES - 1;
        int nhi = dsts[elast];
        for (int s = t >> 5; nlo + s <= nhi; s += 8) {
            int n = nlo + s;
            int b0 = off[n];
            int b1 = (n + 1 < N_NODES) ? off[n + 1] : N_EDGES;
            int lo = b0 > e0 ? b0 : e0;
            int hi = b1 < e0 + EPB ? b1 : e0 + EPB;
            float sum = 0.f;
            for (int j = lo; j < hi; ++j) {
                int jr = j - e0;
                sum += P[(size_t)jr * PLD + c] + P[(size_t)(64 + jr) * PLD + c]
                     + P[(size_t)(128 + jr) * PLD + c] + P[(size_t)(192 + jr) * PLD + c];
            }
            float* ap = agg + (size_t)n * DD + c;
            if (b0 >= e0 && b1 <= e0 + EPB) *ap = sum;     // exclusive owner
            else atomicAdd(ap, sum);                       // boundary node
        }
    }
}

// ---------------------------------------------------------------------------
// conv_gru (R4 proven form): agg read + zero, h in ws, out written last step.
__global__ __launch_bounds__(256) void conv_gru(float* agg,
                                                float* __restrict__ h,
                                                const ushort* __restrict__ wgB,
                                                const float* __restrict__ bconv,
                                                const float* __restrict__ bih,
                                                const float* __restrict__ bhh,
                                                float* out) {
    __shared__ __attribute__((aligned(16))) ushort Ah[64 * 40];   // 5120 B
    __shared__ __attribute__((aligned(16))) ushort Ac[64 * 40];   // 5120 B
    __shared__ float hs[64 * 33];                                 // 8448 B
    __shared__ float bcs[DD], bis[3 * DD], bhs[3 * DD];
    int t = threadIdx.x;
    int base = blockIdx.x * 64;

    for (int idx = t; idx < 64 * DD; idx += 256) {
        int row = idx >> 5, col = idx & 31;
        int n = base + row;
        float v = (n < N_NODES) ? h[(size_t)n * DD + col] : 0.f;
        hs[row * 33 + col] = v;
        Ah[row * 40 + col] = f2b(v);
    }
    if (t < DD) bcs[t] = bconv[t];
    if (t < 3 * DD) { bis[t] = bih[t]; bhs[t] = bhh[t]; }
    __syncthreads();

    int w = t >> 6, l = t & 63;
    int lr = l & 15, lg = l >> 4;
    const f32x4 zro = (f32x4){0.f, 0.f, 0.f, 0.f};

    bf16x8 ah = *(const bf16x8*)(&Ah[(w * 16 + lr) * 40 + lg * 8]);

    // conv GEMM (2 n-tiles, K=32)
    f32x4 dcv[2];
#pragma unroll
    for (int nt = 0; nt < 2; ++nt) {
        bf16x8 b = *(const bf16x8*)(wgB + (size_t)(nt * 64 + l) * 8);
        dcv[nt] = __builtin_amdgcn_mfma_f32_16x16x32_bf16(ah, b, zro, 0, 0, 0);
    }
    // epilogue: + agg + bc, relu -> bf16 Ac; zero agg for next step
#pragma unroll
    for (int nt = 0; nt < 2; ++nt) {
#pragma unroll
        for (int r = 0; r < 4; ++r) {
            int row = w * 16 + lg * 4 + r;
            int col = nt * 16 + lr;
            int n = base + row;
            float a = 0.f;
            if (n < N_NODES) {
                a = agg[(size_t)n * DD + col];
                agg[(size_t)n * DD + col] = 0.f;
            }
            Ac[row * 40 + col] = f2b(fmaxf(dcv[nt][r] + a + bcs[col], 0.f));
        }
    }
    __syncthreads();

    bf16x8 ac = *(const bf16x8*)(&Ac[(w * 16 + lr) * 40 + lg * 8]);

    // gate GEMMs: gi = conv@Wih^T (+bi), gh = h@Whh^T (+bh); 6 n-tiles each
    f32x4 gi[6], gh[6];
#pragma unroll
    for (int nt = 0; nt < 6; ++nt) {
        bf16x8 bi_ = *(const bf16x8*)(wgB + (size_t)(128 + nt * 64 + l) * 8);
        gi[nt] = __builtin_amdgcn_mfma_f32_16x16x32_bf16(ac, bi_, zro, 0, 0, 0);
        bf16x8 bh_ = *(const bf16x8*)(wgB + (size_t)(512 + nt * 64 + l) * 8);
        gh[nt] = __builtin_amdgcn_mfma_f32_16x16x32_bf16(ah, bh_, zro, 0, 0, 0);
    }

    // elementwise GRU in D-layout: col = gate*32 + ch*16 + lr -> tile gate*2+ch
#pragma unroll
    for (int r = 0; r < 4; ++r) {
        int row = w * 16 + lg * 4 + r;
        int n = base + row;
        if (n >= N_NODES) continue;
#pragma unroll
        for (int ch = 0; ch < 2; ++ch) {
            int o = ch * 16 + lr;
            float girv = gi[ch][r]     + bis[o];
            float gizv = gi[2 + ch][r] + bis[DD + o];
            float ginv = gi[4 + ch][r] + bis[2 * DD + o];
            float ghrv = gh[ch][r]     + bhs[o];
            float ghzv = gh[2 + ch][r] + bhs[DD + o];
            float ghnv = gh[4 + ch][r] + bhs[2 * DD + o];
            float R  = 1.f / (1.f + expf(-(girv + ghrv)));
            float Z  = 1.f / (1.f + expf(-(gizv + ghzv)));
            float Nn = tanhf(ginv + R * ghnv);
            float hold = hs[row * 33 + o];
            float hnew = (1.f - Z) * Nn + Z * hold;
            h[(size_t)n * DD + o] = hnew;
            if (out) out[(size_t)n * DD + o] = hnew;
        }
    }
}

// ---------------------------------------------------------------------------
extern "C" void kernel_launch(void* const* d_in, const int* in_sizes, int n_in,
                              void* d_out, int out_size, void* d_ws, size_t ws_size,
                              hipStream_t stream) {
    const float* x    = (const float*)d_in[0];
    const int*   ei   = (const int*)d_in[1];
    const float* ea   = (const float*)d_in[2];
    const float* Wn   = (const float*)d_in[3];
    const float* bn   = (const float*)d_in[4];
    const float* We1  = (const float*)d_in[5];
    const float* be1  = (const float*)d_in[6];
    const float* We2  = (const float*)d_in[7];
    const float* be2  = (const float*)d_in[8];
    const float* Wroot= (const float*)d_in[9];
    const float* bconv= (const float*)d_in[10];
    const float* Wih  = (const float*)d_in[11];
    const float* Whh  = (const float*)d_in[12];
    const float* bih  = (const float*)d_in[13];
    const float* bhh  = (const float*)d_in[14];
    float* out = (float*)d_out;

    // ---- Workspace: 9.09 MB. agg aliases d_out (zeroed/re-zeroed). ----
    char* ws = (char*)d_ws;
    float*  h    = (float*)(ws);                    // 6,400,000 node state
    ushort* we2B = (ushort*)(ws + 6400000);         //   262,144 32x32-frag-major We2T
    ushort* we1B = (ushort*)(ws + 6662144);         //     8,192 fragment-major We1T
    ushort* wgB  = (ushort*)(ws + 6670336);         //    14,336 fragment-major GRU weights
    int*    cnt  = (int*)(ws + 6684672);            //   200,000 hist / local scan
    int*    off  = (int*)(ws + 6884672);            //   200,000 CSR offsets
    int*    cur  = (int*)(ws + 7084672);            //   200,000 fill cursors
    int*    perm = (int*)(ws + 7284672);            //   600,000 sorted-pos -> orig edge
    int*    srcs = (int*)(ws + 7884672);            //   600,000 src ids, sorted order
    int*    dsts = (int*)(ws + 8484672);            //   600,000 dst ids, sorted (asc)
    int*    bsum = (int*)(ws + 9084672);            //     1,024 scan block sums
    float*  agg  = (float*)d_out;                   // 6.4 MB aliases output

    // One-time: merged setup + multi-block scan + fill; agg zeroed once
    hipMemsetAsync(cnt, 0, (size_t)N_NODES * sizeof(int), stream);
    setup<<<852, 256, 0, stream>>>(We2, We1, Wroot, Wih, Whh, we2B, we1B, wgB,
                                   x, Wn, bn, h, ei, cnt);
    scan1<<<NSCAN, 256, 0, stream>>>(cnt, bsum);
    scan2<<<1, 256, 0, stream>>>(bsum);
    scan3<<<NSCAN, 256, 0, stream>>>(cnt, bsum, off, cur);
    scatter_fill<<<(N_EDGES + 255) / 256, 256, 0, stream>>>(ei, cur, perm, srcs, dsts);
    hipMemsetAsync(agg, 0, (size_t)N_NODES * DD * sizeof(float), stream);

    for (int step = 0; step < STEPS; ++step) {
        fused_msg<<<(N_EDGES + EPB - 1) / EPB, 256, 0, stream>>>(ea, we1B, be1, we2B, be2,
                                                                 perm, srcs, dsts, off,
                                                                 h, agg);
        conv_gru<<<(N_NODES + 63) / 64, 256, 0, stream>>>(agg, h, wgB, bconv, bih, bhh,
                                                          (step == STEPS - 1) ? out : nullptr);
    }
}

// Round 10
// 318.191 us; speedup vs baseline: 5.9512x; 5.9512x over previous
//
#include <hip/hip_runtime.h>
#include <hip/hip_bf16.h>

// Problem constants (from reference)
#define N_NODES 50000
#define N_EDGES 150000
#define NODE_IN 64
#define EDGE_IN 16
#define DD 32          // node feature dim
#define EHID 128       // edge-network hidden
#define STEPS 3
#define EPB 64         // edges per fused_msg block: LDS 30208B -> 5 blocks/CU

// Device-verified harness dtypes: float inputs fp32, edge_index int32, output fp32.
__device__ __forceinline__ ushort f2b(float f) {
    __hip_bfloat16 b = __float2bfloat16(f);   // RNE
    return *reinterpret_cast<ushort*>(&b);
}

typedef __bf16 bf16x8 __attribute__((ext_vector_type(8)));
typedef float  f32x4  __attribute__((ext_vector_type(4)));

#define LDA  136   // As leading dim (ushorts)
#define HPAD 36    // Hs leading dim (floats)

// ---------------------------------------------------------------------------
// setup: merged prep + node_init (R10: saves a launch gap; no CSR/hist).
// blocks [0,70): weight repack (R4 16x16-fragment layout); [70,266): node_init.
__global__ __launch_bounds__(256) void setup(const float* __restrict__ we2,
                                             const float* __restrict__ we1,
                                             const float* __restrict__ wroot,
                                             const float* __restrict__ wih,
                                             const float* __restrict__ whh,
                                             ushort* __restrict__ we2B,
                                             ushort* __restrict__ we1B,
                                             ushort* __restrict__ wgB,
                                             const float* __restrict__ x,
                                             const float* __restrict__ Wn,
                                             const float* __restrict__ bn,
                                             float* __restrict__ h) {
    __shared__ float Wns[NODE_IN * DD];   // node_init blocks only
    __shared__ float bns[DD];
    int b = blockIdx.x, t = threadIdx.x;

    if (b < 70) {   // ---- prep (R4-proven 16x16 fragment layout) ----
        int i = b * 256 + t;
        if (i < 16384) {
            int l = i & 63, f = i >> 6;           // f = bn*16 + nt*4 + kt
            int kt = f & 3, nt = (f >> 2) & 3, bq = f >> 4;
            int lr = l & 15, lg = l >> 4;
            int n = bq * 64 + nt * 16 + lr;
            int k0 = kt * 32 + lg * 8;
            ushort tmp[8];
#pragma unroll
            for (int j = 0; j < 8; ++j) tmp[j] = f2b(we2[(size_t)(k0 + j) * 1024 + n]);
            *(uint4*)(we2B + (size_t)i * 8) = *(uint4*)tmp;
        } else if (i < 16896) {
            int u = i - 16384;
            int l = u & 63, nt = u >> 6;
            int lr = l & 15, lg = l >> 4;
            int n = nt * 16 + lr;
            ushort tmp[8];
#pragma unroll
            for (int j = 0; j < 8; ++j) {
                int k = lg * 8 + j;
                tmp[j] = (k < EDGE_IN) ? f2b(we1[(size_t)k * EHID + n]) : (ushort)0;
            }
            *(uint4*)(we1B + (size_t)u * 8) = *(uint4*)tmp;
        } else if (i < 17792) {
            int u = i - 16896;
            int l = u & 63;
            int lr = l & 15, lg = l >> 4;
            ushort tmp[8];
            if (u < 128) {            // Wroot [i][o] row-major
                int nt = u >> 6;
#pragma unroll
                for (int j = 0; j < 8; ++j)
                    tmp[j] = f2b(wroot[(size_t)(lg * 8 + j) * DD + nt * 16 + lr]);
            } else if (u < 512) {     // Wih
                int nt = (u - 128) >> 6;
#pragma unroll
                for (int j = 0; j < 8; ++j)
                    tmp[j] = f2b(wih[(size_t)(nt * 16 + lr) * DD + lg * 8 + j]);
            } else {                  // Whh
                int nt = (u - 512) >> 6;
#pragma unroll
                for (int j = 0; j < 8; ++j)
                    tmp[j] = f2b(whh[(size_t)(nt * 16 + lr) * DD + lg * 8 + j]);
            }
            *(uint4*)(wgB + (size_t)u * 8) = *(uint4*)tmp;
        }
    } else {   // ---- node_init ----
        for (int i = t; i < NODE_IN * DD; i += 256) Wns[i] = Wn[i];
        if (t < DD) bns[t] = bn[t];
        __syncthreads();
        int n = (b - 70) * 256 + t;
        if (n >= N_NODES) return;
        float xr[NODE_IN];
        const float4* xp = (const float4*)(x + (size_t)n * NODE_IN);
#pragma unroll
        for (int q = 0; q < NODE_IN / 4; ++q) *(float4*)&xr[q * 4] = xp[q];
        float out[DD];
#pragma unroll
        for (int o = 0; o < DD; ++o) {
            float s = bns[o];
#pragma unroll
            for (int i = 0; i < NODE_IN; ++i) s += xr[i] * Wns[i * DD + o];
            out[o] = fmaxf(s, 0.f);
        }
        float4* hp = (float4*)(h + (size_t)n * DD);
#pragma unroll
        for (int q = 0; q < DD / 4; ++q) hp[q] = *(float4*)&out[q * 4];
    }
}

// ---------------------------------------------------------------------------
// fused_msg R10: consolidated best-known form. R4 body (16x16 MFMA, LDS-staged
// we2B via global_load_lds, direct ei indexing, atomic scatter) at EPB=64
// (R8-proven occupancy: LDS 30208B -> 5 blocks/CU). No sort, no CSR, no msg
// buffer — total-time ledger says R4's atomic+dense-agg scheme wins.
__global__ __launch_bounds__(256, 5) void fused_msg(const float* __restrict__ ea,
                                                    const ushort* __restrict__ we1B,
                                                    const float* __restrict__ be1,
                                                    const ushort* __restrict__ we2B,
                                                    const float* __restrict__ be2,
                                                    const int* __restrict__ ei,
                                                    const float* __restrict__ h,
                                                    float* __restrict__ agg) {
    // region = max(As 64x136x2 = 17408B, Hs 9216B + Bs 16384B = 25600B)
    __shared__ __attribute__((aligned(16))) ushort AsHs[12800];      // 25600 B
    __shared__ float b1s[EHID];                                      // 512 B
    __shared__ float be2s[DD * DD];                                  // 4096 B
    float* Hs = (float*)AsHs;            // [64][HPAD] fp32 view (phase B)
    ushort* Bs = AsHs + 4608;            // bytes [9216, 25600): bn weight tile

    int t = threadIdx.x;
    if (t < EHID) b1s[t] = be1[t];
    for (int i = t; i < DD * DD; i += 256) be2s[i] = be2[i];

    int w = t >> 6, l = t & 63;
    int lr = l & 15, lg = l >> 4;
    int e0 = blockIdx.x * EPB;

    // Phase A input fragment straight from global (direct, coalesced)
    bf16x8 afe;
    {
        int e = e0 + w * 16 + lr;
        ushort tmp[8] = {0, 0, 0, 0, 0, 0, 0, 0};
        if (lg < 2 && e < N_EDGES) {
            const float4* p = (const float4*)(ea + (size_t)e * EDGE_IN + lg * 8);
            float4 a = p[0], b = p[1];
            tmp[0] = f2b(a.x); tmp[1] = f2b(a.y); tmp[2] = f2b(a.z); tmp[3] = f2b(a.w);
            tmp[4] = f2b(b.x); tmp[5] = f2b(b.y); tmp[6] = f2b(b.z); tmp[7] = f2b(b.w);
        }
        afe = *(bf16x8*)tmp;
    }
    __syncthreads();   // (1) b1s ready

    // Phase A: g = relu(ea@We1+be1) via MFMA -> bf16 As[64][128]
#pragma unroll
    for (int nt = 0; nt < 8; ++nt) {
        bf16x8 bfe = *(const bf16x8*)(we1B + (size_t)((nt << 6) + l) * 8);
        int kh = nt * 16 + lr;
        float bb = b1s[kh];
        f32x4 acc = (f32x4){0.f, 0.f, 0.f, 0.f};
        acc = __builtin_amdgcn_mfma_f32_16x16x32_bf16(afe, bfe, acc, 0, 0, 0);
#pragma unroll
        for (int r = 0; r < 4; ++r)
            AsHs[(w * 16 + lg * 4 + r) * LDA + kh] = f2b(fmaxf(acc[r] + bb, 0.f));
    }
    __syncthreads();   // (2) As complete

    bf16x8 afrag[4];
#pragma unroll
    for (int kt = 0; kt < 4; ++kt)
        afrag[kt] = *(const bf16x8*)(&AsHs[(w * 16 + lr) * LDA + kt * 32 + lg * 8]);
    __syncthreads();   // (3) As reads done -> region becomes Hs + Bs

    // Gather h[src] into Hs (4 threads per edge row)
    {
        int row = t >> 2, qtr = t & 3;
        int e = e0 + row;
        float4* hd = (float4*)(Hs + row * HPAD) + qtr * 2;
        if (e < N_EDGES) {
            const float4* hr = (const float4*)(h + (size_t)ei[e] * DD) + qtr * 2;
            hd[0] = hr[0];
            hd[1] = hr[1];
        } else {
            float4 z = make_float4(0.f, 0.f, 0.f, 0.f);
            hd[0] = z; hd[1] = z;
        }
    }
    // Stage bn=0 weight tile: L2 -> LDS DMA, zero staging VGPRs.
#pragma unroll
    for (int q = 0; q < 4; ++q) {
        const ushort* gsrc = we2B + (size_t)(q * 256 + t) * 8;          // per-lane
        ushort* ldst = Bs + (size_t)(q * 256 + w * 64) * 8;             // wave-uniform
        __builtin_amdgcn_global_load_lds(
            (const __attribute__((address_space(1))) unsigned int*)gsrc,
            (__attribute__((address_space(3))) unsigned int*)ldst, 16, 0, 0);
    }
    asm volatile("s_waitcnt vmcnt(0)" ::: "memory");
    __syncthreads();   // (4) Hs + Bs(0) ready

    float m_acc[4][2];
#pragma unroll
    for (int r = 0; r < 4; ++r) { m_acc[r][0] = 0.f; m_acc[r][1] = 0.f; }

    for (int bn = 0; bn < 16; ++bn) {
        float bv[4];
#pragma unroll
        for (int nt = 0; nt < 4; ++nt) bv[nt] = be2s[bn * 64 + nt * 16 + lr];

        f32x4 acc[4];
#pragma unroll
        for (int nt = 0; nt < 4; ++nt) acc[nt] = (f32x4){0.f, 0.f, 0.f, 0.f};

#pragma unroll
        for (int kt = 0; kt < 4; ++kt) {
            const ushort* base = Bs + (size_t)(kt * 64 + l) * 8;
            bf16x8 b0 = *(const bf16x8*)(base);
            bf16x8 b1 = *(const bf16x8*)(base + 2048);
            bf16x8 b2 = *(const bf16x8*)(base + 4096);
            bf16x8 b3 = *(const bf16x8*)(base + 6144);
            acc[0] = __builtin_amdgcn_mfma_f32_16x16x32_bf16(afrag[kt], b0, acc[0], 0, 0, 0);
            acc[1] = __builtin_amdgcn_mfma_f32_16x16x32_bf16(afrag[kt], b1, acc[1], 0, 0, 0);
            acc[2] = __builtin_amdgcn_mfma_f32_16x16x32_bf16(afrag[kt], b2, acc[2], 0, 0, 0);
            acc[3] = __builtin_amdgcn_mfma_f32_16x16x32_bf16(afrag[kt], b3, acc[3], 0, 0, 0);
        }

        // Fold: col=bn*64+nt*16+lr -> i=2bn+(nt>>1), o=16*(nt&1)+lr
#pragma unroll
        for (int r = 0; r < 4; ++r) {
            int row = w * 16 + lg * 4 + r;
            float2 hv = *(const float2*)(Hs + row * HPAD + bn * 2);
#pragma unroll
            for (int nt = 0; nt < 4; ++nt) {
                float hi = (nt >> 1) ? hv.y : hv.x;
                m_acc[r][nt & 1] += hi * (acc[nt][r] + bv[nt]);
            }
        }

        if (bn < 15) {
            __syncthreads();   // all waves done reading Bs(bn)
#pragma unroll
            for (int q = 0; q < 4; ++q) {
                const ushort* gsrc = we2B + (size_t)(bn + 1) * 8192 + (size_t)(q * 256 + t) * 8;
                ushort* ldst = Bs + (size_t)(q * 256 + w * 64) * 8;
                __builtin_amdgcn_global_load_lds(
                    (const __attribute__((address_space(1))) unsigned int*)gsrc,
                    (__attribute__((address_space(3))) unsigned int*)ldst, 16, 0, 0);
            }
            asm volatile("s_waitcnt vmcnt(0)" ::: "memory");
            __syncthreads();   // Bs(bn+1) ready
        }
    }

    // Scatter: agg[dst] += m (atomic; register-direct, no extra barrier)
#pragma unroll
    for (int r = 0; r < 4; ++r) {
        int le = w * 16 + lg * 4 + r;
        int e = e0 + le;
        if (e < N_EDGES) {
            int dst = ei[N_EDGES + e];
            float* ar = agg + (size_t)dst * DD;
            atomicAdd(ar + lr,      m_acc[r][0]);
            atomicAdd(ar + lr + 16, m_acc[r][1]);
        }
    }
}

// ---------------------------------------------------------------------------
// conv_gru (R4 proven form): agg aliases out (agg lives in d_out). No
// __restrict__ on agg/out; each (row,col) read+zeroed then re-written by the
// SAME thread in program order; blocks own disjoint rows.
__global__ __launch_bounds__(256) void conv_gru(float* agg,
                                                float* __restrict__ h,
                                                const ushort* __restrict__ wgB,
                                                const float* __restrict__ bconv,
                                                const float* __restrict__ bih,
                                                const float* __restrict__ bhh,
                                                float* out) {
    __shared__ __attribute__((aligned(16))) ushort Ah[64 * 40];   // 5120 B
    __shared__ __attribute__((aligned(16))) ushort Ac[64 * 40];   // 5120 B
    __shared__ float hs[64 * 33];                                 // 8448 B
    __shared__ float bcs[DD], bis[3 * DD], bhs[3 * DD];
    int t = threadIdx.x;
    int base = blockIdx.x * 64;

    for (int idx = t; idx < 64 * DD; idx += 256) {
        int row = idx >> 5, col = idx & 31;
        int n = base + row;
        float v = (n < N_NODES) ? h[(size_t)n * DD + col] : 0.f;
        hs[row * 33 + col] = v;
        Ah[row * 40 + col] = f2b(v);
    }
    if (t < DD) bcs[t] = bconv[t];
    if (t < 3 * DD) { bis[t] = bih[t]; bhs[t] = bhh[t]; }
    __syncthreads();

    int w = t >> 6, l = t & 63;
    int lr = l & 15, lg = l >> 4;
    const f32x4 zro = (f32x4){0.f, 0.f, 0.f, 0.f};

    bf16x8 ah = *(const bf16x8*)(&Ah[(w * 16 + lr) * 40 + lg * 8]);

    // conv GEMM (2 n-tiles, K=32)
    f32x4 dcv[2];
#pragma unroll
    for (int nt = 0; nt < 2; ++nt) {
        bf16x8 b = *(const bf16x8*)(wgB + (size_t)(nt * 64 + l) * 8);
        dcv[nt] = __builtin_amdgcn_mfma_f32_16x16x32_bf16(ah, b, zro, 0, 0, 0);
    }
    // epilogue: + agg + bc, relu -> bf16 Ac; zero agg for next step
#pragma unroll
    for (int nt = 0; nt < 2; ++nt) {
#pragma unroll
        for (int r = 0; r < 4; ++r) {
            int row = w * 16 + lg * 4 + r;
            int col = nt * 16 + lr;
            int n = base + row;
            float a = 0.f;
            if (n < N_NODES) {
                a = agg[(size_t)n * DD + col];
                agg[(size_t)n * DD + col] = 0.f;
            }
            Ac[row * 40 + col] = f2b(fmaxf(dcv[nt][r] + a + bcs[col], 0.f));
        }
    }
    __syncthreads();

    bf16x8 ac = *(const bf16x8*)(&Ac[(w * 16 + lr) * 40 + lg * 8]);

    // gate GEMMs: gi = conv@Wih^T (+bi), gh = h@Whh^T (+bh); 6 n-tiles each
    f32x4 gi[6], gh[6];
#pragma unroll
    for (int nt = 0; nt < 6; ++nt) {
        bf16x8 bi_ = *(const bf16x8*)(wgB + (size_t)(128 + nt * 64 + l) * 8);
        gi[nt] = __builtin_amdgcn_mfma_f32_16x16x32_bf16(ac, bi_, zro, 0, 0, 0);
        bf16x8 bh_ = *(const bf16x8*)(wgB + (size_t)(512 + nt * 64 + l) * 8);
        gh[nt] = __builtin_amdgcn_mfma_f32_16x16x32_bf16(ah, bh_, zro, 0, 0, 0);
    }

    // elementwise GRU in D-layout: col = gate*32 + ch*16 + lr -> tile gate*2+ch
#pragma unroll
    for (int r = 0; r < 4; ++r) {
        int row = w * 16 + lg * 4 + r;
        int n = base + row;
        if (n >= N_NODES) continue;
#pragma unroll
        for (int ch = 0; ch < 2; ++ch) {
            int o = ch * 16 + lr;
            float girv = gi[ch][r]     + bis[o];
            float gizv = gi[2 + ch][r] + bis[DD + o];
            float ginv = gi[4 + ch][r] + bis[2 * DD + o];
            float ghrv = gh[ch][r]     + bhs[o];
            float ghzv = gh[2 + ch][r] + bhs[DD + o];
            float ghnv = gh[4 + ch][r] + bhs[2 * DD + o];
            float R  = 1.f / (1.f + expf(-(girv + ghrv)));
            float Z  = 1.f / (1.f + expf(-(gizv + ghzv)));
            float Nn = tanhf(ginv + R * ghnv);
            float hold = hs[row * 33 + o];
            float hnew = (1.f - Z) * Nn + Z * hold;
            h[(size_t)n * DD + o] = hnew;
            if (out) out[(size_t)n * DD + o] = hnew;
        }
    }
}

// ---------------------------------------------------------------------------
extern "C" void kernel_launch(void* const* d_in, const int* in_sizes, int n_in,
                              void* d_out, int out_size, void* d_ws, size_t ws_size,
                              hipStream_t stream) {
    const float* x    = (const float*)d_in[0];
    const int*   ei   = (const int*)d_in[1];
    const float* ea   = (const float*)d_in[2];
    const float* Wn   = (const float*)d_in[3];
    const float* bn   = (const float*)d_in[4];
    const float* We1  = (const float*)d_in[5];
    const float* be1  = (const float*)d_in[6];
    const float* We2  = (const float*)d_in[7];
    const float* be2  = (const float*)d_in[8];
    const float* Wroot= (const float*)d_in[9];
    const float* bconv= (const float*)d_in[10];
    const float* Wih  = (const float*)d_in[11];
    const float* Whh  = (const float*)d_in[12];
    const float* bih  = (const float*)d_in[13];
    const float* bhh  = (const float*)d_in[14];
    float* out = (float*)d_out;   // fp32 output

    // ---- Workspace: 6.68 MB (R4 layout; agg aliases d_out) ----
    char* ws = (char*)d_ws;
    float*  h    = (float*)(ws);                    // 6,400,000
    ushort* we2B = (ushort*)(ws + 6400000);         //   262,144 fragment-major We2T
    ushort* we1B = (ushort*)(ws + 6662144);         //     8,192 fragment-major We1T
    ushort* wgB  = (ushort*)(ws + 6670336);         //    14,336 fragment-major GRU weights
    float*  agg  = (float*)d_out;                   // aliases output buffer

    setup<<<266, 256, 0, stream>>>(We2, We1, Wroot, Wih, Whh, we2B, we1B, wgB,
                                   x, Wn, bn, h);
    hipMemsetAsync(agg, 0, (size_t)N_NODES * DD * sizeof(float), stream);

    for (int step = 0; step < STEPS; ++step) {
        fused_msg<<<(N_EDGES + EPB - 1) / EPB, 256, 0, stream>>>(ea, we1B, be1, we2B, be2,
                                                                 ei, h, agg);
        conv_gru<<<(N_NODES + 63) / 64, 256, 0, stream>>>(agg, h, wgB, bconv, bih, bhh,
                                                          (step == STEPS - 1) ? out : nullptr);
    }
}